// Round 7
// baseline (13758.243 us; speedup 1.0000x reference)
//
#include <hip/hip_runtime.h>
#include <hip/hip_bf16.h>
#include <math.h>

#define TT 100
#define ND 10
#define DS 6
#define SAW 2816

typedef _Float16 half8 __attribute__((ext_vector_type(8)));
typedef float floatx4 __attribute__((ext_vector_type(4)));

__device__ __forceinline__ void gload_lds16(const _Float16* g, _Float16* l) {
    __builtin_amdgcn_global_load_lds((const __attribute__((address_space(1))) void*)g,
                                     (__attribute__((address_space(3))) void*)l, 16, 0, 0);
}

// ---------------------------------------------------------------------------
// K1: gates = inp @ W_ih_ilv^T (K=256) with acc init from ghh(t-1);
// epilogue: +biases -> LSTM -> c, h -> z[:,256:] & x[:,2560:]; then emb(t).
// Interleaved N: col j -> channel j>>2, gate j&3. 64x64 tiles, grid (8,16).
// ---------------------------------------------------------------------------
__global__ __launch_bounds__(256) void gates_lstm_emb(
    const _Float16* __restrict__ zrhi, const _Float16* __restrict__ zrlo,
    const _Float16* __restrict__ wihhi, const _Float16* __restrict__ wihlo,
    const float* __restrict__ ghh,
    const float* __restrict__ b_ih, const float* __restrict__ b_hh,
    float* __restrict__ cbuf,
    _Float16* __restrict__ zwhi, _Float16* __restrict__ zwlo,
    _Float16* __restrict__ xhi, _Float16* __restrict__ xlo,
    const float* __restrict__ desc, const float* __restrict__ Wd,
    const float* __restrict__ bd, int t)
{
    __shared__ alignas(16) _Float16 sAh[64 * 32];
    __shared__ alignas(16) _Float16 sAl[64 * 32];
    __shared__ alignas(16) _Float16 sBh[64 * 32];
    __shared__ alignas(16) _Float16 sBl[64 * 32];
    __shared__ float sg[64][68];

    const int tid = threadIdx.x, w = tid >> 6, l = tid & 63;
    const int m0 = blockIdx.x * 64, n0 = blockIdx.y * 64;
    const int sr = 16 * w + (l >> 2), sc = (l & 3) * 8, sidx = sr * 32 + sc;
    const _Float16* gAh = zrhi + (size_t)(m0 + sr) * 512 + sc;       // inp cols 0..255
    const _Float16* gAl = zrlo + (size_t)(m0 + sr) * 512 + sc;
    const _Float16* gBh = wihhi + (size_t)(n0 + sr) * 256 + sc;
    const _Float16* gBl = wihlo + (size_t)(n0 + sr) * 256 + sc;
    const int mw = (w >> 1) * 32, nw = (w & 1) * 32;
    const int fr = l & 15, fk = (l >> 4) * 8;
    const int cr = (l >> 4) * 4, cc = l & 15;

    floatx4 acc[2][2];
#pragma unroll
    for (int mf = 0; mf < 2; ++mf)
#pragma unroll
        for (int nf = 0; nf < 2; ++nf)
#pragma unroll
            for (int r = 0; r < 4; ++r)
                acc[mf][nf][r] = ghh[(size_t)(m0 + mw + mf * 16 + cr + r) * 1024
                                     + (n0 + nw + nf * 16 + cc)];

    half8 rAh = *(const half8*)gAh;
    half8 rAl = *(const half8*)gAl;
    half8 rBh = *(const half8*)gBh;
    half8 rBl = *(const half8*)gBl;

    for (int kt = 0; kt < 256; kt += 32) {
        *(half8*)&sAh[sidx] = rAh;
        *(half8*)&sAl[sidx] = rAl;
        *(half8*)&sBh[sidx] = rBh;
        *(half8*)&sBl[sidx] = rBl;
        __syncthreads();
        if (kt + 32 < 256) {
            rAh = *(const half8*)(gAh + kt + 32);
            rAl = *(const half8*)(gAl + kt + 32);
            rBh = *(const half8*)(gBh + kt + 32);
            rBl = *(const half8*)(gBl + kt + 32);
        }
        half8 aH[2], aL[2], bH[2], bL[2];
#pragma unroll
        for (int mf = 0; mf < 2; ++mf) {
            const int ro = (mw + mf * 16 + fr) * 32 + fk;
            aH[mf] = *(const half8*)&sAh[ro];
            aL[mf] = *(const half8*)&sAl[ro];
        }
#pragma unroll
        for (int nf = 0; nf < 2; ++nf) {
            const int ro = (nw + nf * 16 + fr) * 32 + fk;
            bH[nf] = *(const half8*)&sBh[ro];
            bL[nf] = *(const half8*)&sBl[ro];
        }
#pragma unroll
        for (int mf = 0; mf < 2; ++mf)
#pragma unroll
            for (int nf = 0; nf < 2; ++nf)
                acc[mf][nf] = __builtin_amdgcn_mfma_f32_16x16x32_f16(aH[mf], bH[nf], acc[mf][nf], 0, 0, 0);
#pragma unroll
        for (int mf = 0; mf < 2; ++mf)
#pragma unroll
            for (int nf = 0; nf < 2; ++nf)
                acc[mf][nf] = __builtin_amdgcn_mfma_f32_16x16x32_f16(aH[mf], bL[nf], acc[mf][nf], 0, 0, 0);
#pragma unroll
        for (int mf = 0; mf < 2; ++mf)
#pragma unroll
            for (int nf = 0; nf < 2; ++nf)
                acc[mf][nf] = __builtin_amdgcn_mfma_f32_16x16x32_f16(aL[mf], bH[nf], acc[mf][nf], 0, 0, 0);
        __syncthreads();
    }

    // gates tile -> LDS
#pragma unroll
    for (int mf = 0; mf < 2; ++mf)
#pragma unroll
        for (int nf = 0; nf < 2; ++nf)
#pragma unroll
            for (int r = 0; r < 4; ++r)
                sg[mw + mf * 16 + cr + r][nw + nf * 16 + cc] = acc[mf][nf][r];
    __syncthreads();

    // LSTM: 64 rows x 16 channels per block
    const int q0 = blockIdx.y * 16;
#pragma unroll
    for (int it = 0; it < 4; ++it) {
        const int idx = it * 256 + tid;
        const int r_ = idx >> 4, ch = idx & 15;
        const int b = m0 + r_, gq = q0 + ch;
        const float gi = sg[r_][4 * ch + 0] + b_ih[gq]       + b_hh[gq];
        const float gf = sg[r_][4 * ch + 1] + b_ih[256 + gq] + b_hh[256 + gq];
        const float gg = sg[r_][4 * ch + 2] + b_ih[512 + gq] + b_hh[512 + gq];
        const float go = sg[r_][4 * ch + 3] + b_ih[768 + gq] + b_hh[768 + gq];
        const float si = 1.f / (1.f + expf(-gi));
        const float sf = 1.f / (1.f + expf(-gf));
        const float so = 1.f / (1.f + expf(-go));
        float cv = cbuf[b * 256 + gq];
        cv = sf * cv + si * tanhf(gg);
        const float hv = so * tanhf(cv);
        cbuf[b * 256 + gq] = cv;
        const _Float16 h = (_Float16)hv;
        const _Float16 lo = (_Float16)(hv - (float)h);
        zwhi[b * 512 + 256 + gq] = h;
        zwlo[b * 512 + 256 + gq] = lo;
        xhi[(size_t)b * SAW + 2560 + gq] = h;
        xlo[(size_t)b * SAW + 2560 + gq] = lo;
    }

    // emb(t): rows [m0,m0+64), cols [by*160, +160)
    const int c0 = blockIdx.y * 160;
    for (int idx = tid; idx < 64 * 160; idx += 256) {
        const int r_ = idx / 160, c = c0 + idx % 160;
        const int b = m0 + r_, n = c >> 8, i = c & 255;
        float a = bd[i];
        const float* dp = desc + ((size_t)b * TT + t) * 60 + n * 6;
#pragma unroll
        for (int d = 0; d < 6; ++d) a += dp[d] * Wd[i * 6 + d];
        const _Float16 h = (_Float16)a;
        xhi[(size_t)b * SAW + c] = h;
        xlo[(size_t)b * SAW + c] = (_Float16)(a - (float)h);
    }
}

// ---------------------------------------------------------------------------
// Kg: ghh(t) = h(t) @ W_hh_ilv^T (K=256) -> f32 [512][1024] interleaved
// ---------------------------------------------------------------------------
__global__ __launch_bounds__(256) void ghh_gemm(
    const _Float16* __restrict__ zhi, const _Float16* __restrict__ zlo,
    const _Float16* __restrict__ whhhi, const _Float16* __restrict__ whhlo,
    float* __restrict__ ghh)
{
    __shared__ alignas(16) _Float16 sAh[64 * 32];
    __shared__ alignas(16) _Float16 sAl[64 * 32];
    __shared__ alignas(16) _Float16 sBh[64 * 32];
    __shared__ alignas(16) _Float16 sBl[64 * 32];

    const int tid = threadIdx.x, w = tid >> 6, l = tid & 63;
    const int m0 = blockIdx.x * 64, n0 = blockIdx.y * 64;
    const int sr = 16 * w + (l >> 2), sc = (l & 3) * 8, sidx = sr * 32 + sc;
    const _Float16* gAh = zhi + (size_t)(m0 + sr) * 512 + 256 + sc;   // h cols
    const _Float16* gAl = zlo + (size_t)(m0 + sr) * 512 + 256 + sc;
    const _Float16* gBh = whhhi + (size_t)(n0 + sr) * 256 + sc;
    const _Float16* gBl = whhlo + (size_t)(n0 + sr) * 256 + sc;
    const int mw = (w >> 1) * 32, nw = (w & 1) * 32;
    const int fr = l & 15, fk = (l >> 4) * 8;

    floatx4 acc[2][2];
    const floatx4 z4 = {0.f, 0.f, 0.f, 0.f};
#pragma unroll
    for (int i = 0; i < 2; ++i)
#pragma unroll
        for (int j = 0; j < 2; ++j) acc[i][j] = z4;

    half8 rAh = *(const half8*)gAh;
    half8 rAl = *(const half8*)gAl;
    half8 rBh = *(const half8*)gBh;
    half8 rBl = *(const half8*)gBl;

    for (int kt = 0; kt < 256; kt += 32) {
        *(half8*)&sAh[sidx] = rAh;
        *(half8*)&sAl[sidx] = rAl;
        *(half8*)&sBh[sidx] = rBh;
        *(half8*)&sBl[sidx] = rBl;
        __syncthreads();
        if (kt + 32 < 256) {
            rAh = *(const half8*)(gAh + kt + 32);
            rAl = *(const half8*)(gAl + kt + 32);
            rBh = *(const half8*)(gBh + kt + 32);
            rBl = *(const half8*)(gBl + kt + 32);
        }
        half8 aH[2], aL[2], bH[2], bL[2];
#pragma unroll
        for (int mf = 0; mf < 2; ++mf) {
            const int ro = (mw + mf * 16 + fr) * 32 + fk;
            aH[mf] = *(const half8*)&sAh[ro];
            aL[mf] = *(const half8*)&sAl[ro];
        }
#pragma unroll
        for (int nf = 0; nf < 2; ++nf) {
            const int ro = (nw + nf * 16 + fr) * 32 + fk;
            bH[nf] = *(const half8*)&sBh[ro];
            bL[nf] = *(const half8*)&sBl[ro];
        }
#pragma unroll
        for (int mf = 0; mf < 2; ++mf)
#pragma unroll
            for (int nf = 0; nf < 2; ++nf)
                acc[mf][nf] = __builtin_amdgcn_mfma_f32_16x16x32_f16(aH[mf], bH[nf], acc[mf][nf], 0, 0, 0);
#pragma unroll
        for (int mf = 0; mf < 2; ++mf)
#pragma unroll
            for (int nf = 0; nf < 2; ++nf)
                acc[mf][nf] = __builtin_amdgcn_mfma_f32_16x16x32_f16(aH[mf], bL[nf], acc[mf][nf], 0, 0, 0);
#pragma unroll
        for (int mf = 0; mf < 2; ++mf)
#pragma unroll
            for (int nf = 0; nf < 2; ++nf)
                acc[mf][nf] = __builtin_amdgcn_mfma_f32_16x16x32_f16(aL[mf], bH[nf], acc[mf][nf], 0, 0, 0);
        __syncthreads();
    }

    const int cr = (l >> 4) * 4, cc = l & 15;
#pragma unroll
    for (int mf = 0; mf < 2; ++mf)
#pragma unroll
        for (int nf = 0; nf < 2; ++nf)
#pragma unroll
            for (int r = 0; r < 4; ++r)
                ghh[(size_t)(m0 + mw + mf * 16 + cr + r) * 1024
                    + (n0 + nw + nf * 16 + cc)] = acc[mf][nf][r];
}

// ---------------------------------------------------------------------------
// K2: W1 big-tile GEMM, 128x128, (4,22,4); atomicAdd into ybuf f32;
// last arriver per tile: +b1, relu, hi/lo split -> y planes; re-zero ybuf.
// ---------------------------------------------------------------------------
__global__ __launch_bounds__(256) void w1_atomic(
    const _Float16* __restrict__ Ah, const _Float16* __restrict__ Al,
    const _Float16* __restrict__ Bh, const _Float16* __restrict__ Bl,
    float* __restrict__ ybuf, const float* __restrict__ b1,
    _Float16* __restrict__ yhi, _Float16* __restrict__ ylo,
    int* __restrict__ ctr)
{
    __shared__ alignas(16) _Float16 lds[4 * 128 * 32];
    __shared__ int isLast;

    const int tid = threadIdx.x;
    const int w = tid >> 6, l = tid & 63;
    const int m0 = blockIdx.x * 128, n0 = blockIdx.y * 128;
    const int koff = blockIdx.z * 704;

    const _Float16* plane_src;
    if (w == 0)      plane_src = Ah + (size_t)m0 * SAW;
    else if (w == 1) plane_src = Al + (size_t)m0 * SAW;
    else if (w == 2) plane_src = Bh + (size_t)n0 * SAW;
    else             plane_src = Bl + (size_t)n0 * SAW;
    const int srow_in_chunk = l >> 2;
    const int scol = (l & 3) * 8;
    _Float16* const lds_plane = lds + w * 4096;

    const int wr = (w >> 1) * 64, wc = (w & 1) * 64;
    const int fr = l & 15, fk = (l >> 4) * 8;

    floatx4 acc[4][4];
    const floatx4 z4 = {0.f, 0.f, 0.f, 0.f};
#pragma unroll
    for (int i = 0; i < 4; ++i)
#pragma unroll
        for (int j = 0; j < 4; ++j) acc[i][j] = z4;

    for (int kt = 0; kt < 704; kt += 32) {
        __syncthreads();
#pragma unroll
        for (int i = 0; i < 8; ++i) {
            const int row = i * 16 + srow_in_chunk;
            gload_lds16(plane_src + (size_t)row * SAW + koff + kt + scol,
                        lds_plane + i * 512);
        }
        __syncthreads();

        half8 aH[4], aL[4], bH[4], bL[4];
#pragma unroll
        for (int f = 0; f < 4; ++f) {
            const int ra = (wr + f * 16 + fr) * 32 + fk;
            const int rb = (wc + f * 16 + fr) * 32 + fk;
            aH[f] = *(const half8*)&lds[ra];
            aL[f] = *(const half8*)&lds[4096 + ra];
            bH[f] = *(const half8*)&lds[8192 + rb];
            bL[f] = *(const half8*)&lds[12288 + rb];
        }
#pragma unroll
        for (int mf = 0; mf < 4; ++mf)
#pragma unroll
            for (int nf = 0; nf < 4; ++nf)
                acc[mf][nf] = __builtin_amdgcn_mfma_f32_16x16x32_f16(aH[mf], bH[nf], acc[mf][nf], 0, 0, 0);
#pragma unroll
        for (int mf = 0; mf < 4; ++mf)
#pragma unroll
            for (int nf = 0; nf < 4; ++nf)
                acc[mf][nf] = __builtin_amdgcn_mfma_f32_16x16x32_f16(aH[mf], bL[nf], acc[mf][nf], 0, 0, 0);
#pragma unroll
        for (int mf = 0; mf < 4; ++mf)
#pragma unroll
            for (int nf = 0; nf < 4; ++nf)
                acc[mf][nf] = __builtin_amdgcn_mfma_f32_16x16x32_f16(aL[mf], bH[nf], acc[mf][nf], 0, 0, 0);
    }

    const int cr = (l >> 4) * 4, cc = l & 15;
#pragma unroll
    for (int mf = 0; mf < 4; ++mf) {
        const int row = m0 + wr + mf * 16 + cr;
#pragma unroll
        for (int nf = 0; nf < 4; ++nf) {
            const int col = n0 + wc + nf * 16 + cc;
#pragma unroll
            for (int r = 0; r < 4; ++r)
                atomicAdd(&ybuf[(size_t)(row + r) * SAW + col], acc[mf][nf][r]);
        }
    }
    __threadfence();
    if (tid == 0) {
        const int old = atomicAdd(&ctr[blockIdx.y * 4 + blockIdx.x], 1);
        isLast = ((old & 3) == 3);
    }
    __syncthreads();
    if (isLast) {
        __threadfence();
#pragma unroll
        for (int k = 0; k < 64; ++k) {
            const int idx = k * 256 + tid;
            const int row = m0 + (idx >> 7), col = n0 + (idx & 127);
            const size_t o = (size_t)row * SAW + col;
            float s = ybuf[o];
            ybuf[o] = 0.f;
            float v = s + b1[col];
            v = v > 0.f ? v : 0.f;
            const _Float16 h = (_Float16)v;
            yhi[o] = h;
            ylo[o] = (_Float16)(v - (float)h);
        }
    }
}

// ---------------------------------------------------------------------------
// K3: W2v (W2 rows 0..255, Wv rows 256..265, zero pad to 272) 64x64 (8,5,4);
// atomicAdd into w2acc; last arriver: cols<256 -> inp (z[:, :256]) with
// bias+relu+split; cols 256..265 -> out[b,t,n]+bv; re-zero.
// ---------------------------------------------------------------------------
__global__ __launch_bounds__(256) void w2v_atomic(
    const _Float16* __restrict__ yhi, const _Float16* __restrict__ ylo,
    const _Float16* __restrict__ Bh, const _Float16* __restrict__ Bl,
    float* __restrict__ w2acc, const float* __restrict__ b2,
    const float* __restrict__ bv,
    _Float16* __restrict__ zhi, _Float16* __restrict__ zlo,
    float* __restrict__ out, int* __restrict__ ctr, int t)
{
    __shared__ alignas(16) _Float16 sAh[64 * 32];
    __shared__ alignas(16) _Float16 sAl[64 * 32];
    __shared__ alignas(16) _Float16 sBh[64 * 32];
    __shared__ alignas(16) _Float16 sBl[64 * 32];
    __shared__ int isLast;

    const int tid = threadIdx.x, w = tid >> 6, l = tid & 63;
    const int m0 = blockIdx.x * 64, n0 = blockIdx.y * 64;
    const int koff = blockIdx.z * 704;

    const int sr = 16 * w + (l >> 2), sc = (l & 3) * 8, sidx = sr * 32 + sc;
    const int brow = min(n0 + sr, 271);
    const _Float16* gAh = yhi + (size_t)(m0 + sr) * SAW + koff + sc;
    const _Float16* gAl = ylo + (size_t)(m0 + sr) * SAW + koff + sc;
    const _Float16* gBh = Bh + (size_t)brow * SAW + koff + sc;
    const _Float16* gBl = Bl + (size_t)brow * SAW + koff + sc;
    const int mw = (w >> 1) * 32, nw = (w & 1) * 32;
    const int fr = l & 15, fk = (l >> 4) * 8;

    floatx4 acc[2][2];
    const floatx4 z4 = {0.f, 0.f, 0.f, 0.f};
#pragma unroll
    for (int i = 0; i < 2; ++i)
#pragma unroll
        for (int j = 0; j < 2; ++j) acc[i][j] = z4;

    half8 rAh = *(const half8*)gAh;
    half8 rAl = *(const half8*)gAl;
    half8 rBh = *(const half8*)gBh;
    half8 rBl = *(const half8*)gBl;

    for (int kt = 0; kt < 704; kt += 32) {
        *(half8*)&sAh[sidx] = rAh;
        *(half8*)&sAl[sidx] = rAl;
        *(half8*)&sBh[sidx] = rBh;
        *(half8*)&sBl[sidx] = rBl;
        __syncthreads();
        if (kt + 32 < 704) {
            rAh = *(const half8*)(gAh + kt + 32);
            rAl = *(const half8*)(gAl + kt + 32);
            rBh = *(const half8*)(gBh + kt + 32);
            rBl = *(const half8*)(gBl + kt + 32);
        }
        half8 aH[2], aL[2], bH[2], bL[2];
#pragma unroll
        for (int mf = 0; mf < 2; ++mf) {
            const int ro = (mw + mf * 16 + fr) * 32 + fk;
            aH[mf] = *(const half8*)&sAh[ro];
            aL[mf] = *(const half8*)&sAl[ro];
        }
#pragma unroll
        for (int nf = 0; nf < 2; ++nf) {
            const int ro = (nw + nf * 16 + fr) * 32 + fk;
            bH[nf] = *(const half8*)&sBh[ro];
            bL[nf] = *(const half8*)&sBl[ro];
        }
#pragma unroll
        for (int mf = 0; mf < 2; ++mf)
#pragma unroll
            for (int nf = 0; nf < 2; ++nf)
                acc[mf][nf] = __builtin_amdgcn_mfma_f32_16x16x32_f16(aH[mf], bH[nf], acc[mf][nf], 0, 0, 0);
#pragma unroll
        for (int mf = 0; mf < 2; ++mf)
#pragma unroll
            for (int nf = 0; nf < 2; ++nf)
                acc[mf][nf] = __builtin_amdgcn_mfma_f32_16x16x32_f16(aH[mf], bL[nf], acc[mf][nf], 0, 0, 0);
#pragma unroll
        for (int mf = 0; mf < 2; ++mf)
#pragma unroll
            for (int nf = 0; nf < 2; ++nf)
                acc[mf][nf] = __builtin_amdgcn_mfma_f32_16x16x32_f16(aL[mf], bH[nf], acc[mf][nf], 0, 0, 0);
        __syncthreads();
    }

    const int cr = (l >> 4) * 4, cc = l & 15;
#pragma unroll
    for (int nf = 0; nf < 2; ++nf) {
        const int col = n0 + nw + nf * 16 + cc;
#pragma unroll
        for (int mf = 0; mf < 2; ++mf) {
            const int row = m0 + mw + mf * 16 + cr;
#pragma unroll
            for (int r = 0; r < 4; ++r)
                atomicAdd(&w2acc[(row + r) * 320 + col], acc[mf][nf][r]);
        }
    }
    __threadfence();
    if (tid == 0) {
        const int old = atomicAdd(&ctr[blockIdx.y * 8 + blockIdx.x], 1);
        isLast = ((old & 3) == 3);
    }
    __syncthreads();
    if (isLast) {
        __threadfence();
#pragma unroll
        for (int k = 0; k < 16; ++k) {
            const int idx = k * 256 + tid;
            const int row = m0 + (idx >> 6), col = n0 + (idx & 63);
            float s = w2acc[row * 320 + col];
            w2acc[row * 320 + col] = 0.f;
            if (col < 256) {
                float v = s + b2[col];
                v = v > 0.f ? v : 0.f;
                const _Float16 h = (_Float16)v;
                zhi[row * 512 + col] = h;
                zlo[row * 512 + col] = (_Float16)(v - (float)h);
            } else if (col < 266) {
                out[(size_t)row * (TT * ND) + t * ND + (col - 256)] = s + bv[col - 256];
            }
        }
    }
}

// ---------------------------------------------------------------------------
// prep: interleaved LSTM weight splits; W1 split; W2|Wv concat split (272 rows)
// ---------------------------------------------------------------------------
__global__ void build_ilv(const float* __restrict__ W_ih, const float* __restrict__ W_hh,
                          _Float16* __restrict__ wihhi, _Float16* __restrict__ wihlo,
                          _Float16* __restrict__ whhhi, _Float16* __restrict__ whhlo)
{
    const int j = blockIdx.x, k = threadIdx.x;          // j interleaved row
    const int orow = (j & 3) * 256 + (j >> 2);
    float v = W_ih[orow * 256 + k];
    _Float16 h = (_Float16)v;
    wihhi[j * 256 + k] = h;
    wihlo[j * 256 + k] = (_Float16)(v - (float)h);
    v = W_hh[orow * 256 + k];
    h = (_Float16)v;
    whhhi[j * 256 + k] = h;
    whhlo[j * 256 + k] = (_Float16)(v - (float)h);
}

__global__ __launch_bounds__(256) void build_w2v(const float* __restrict__ W2,
                                                 const float* __restrict__ Wv,
                                                 _Float16* __restrict__ hi,
                                                 _Float16* __restrict__ lo)
{
    const int j = blockIdx.x;                            // 0..271
    for (int k = threadIdx.x; k < SAW; k += 256) {
        float v = 0.f;
        if (j < 256)       v = W2[(size_t)j * SAW + k];
        else if (j < 266)  v = Wv[(size_t)(j - 256) * SAW + k];
        const _Float16 h = (_Float16)v;
        hi[(size_t)j * SAW + k] = h;
        lo[(size_t)j * SAW + k] = (_Float16)(v - (float)h);
    }
}

__global__ __launch_bounds__(256) void cvt_hilo(const float* __restrict__ src,
                                                _Float16* __restrict__ hi,
                                                _Float16* __restrict__ lo, int n)
{
    int i = blockIdx.x * 256 + threadIdx.x;
    const int stride = gridDim.x * 256;
    for (; i < n; i += stride) {
        const float v = src[i];
        const _Float16 h = (_Float16)v;
        hi[i] = h;
        lo[i] = (_Float16)(v - (float)h);
    }
}

// ---------------------------------------------------------------------------
extern "C" void kernel_launch(void* const* d_in, const int* in_sizes, int n_in,
                              void* d_out, int out_size, void* d_ws, size_t ws_size,
                              hipStream_t stream)
{
    const float* desc = (const float*)d_in[0];
    const float* Wd   = (const float*)d_in[1];
    const float* bd   = (const float*)d_in[2];
    const float* W1   = (const float*)d_in[3];
    const float* b1   = (const float*)d_in[4];
    const float* W2   = (const float*)d_in[5];
    const float* b2   = (const float*)d_in[6];
    const float* Wv   = (const float*)d_in[7];
    const float* bv   = (const float*)d_in[8];
    const float* W_ih = (const float*)d_in[9];
    const float* W_hh = (const float*)d_in[10];
    const float* b_ih = (const float*)d_in[11];
    const float* b_hh = (const float*)d_in[12];
    float* out = (float*)d_out;

    char* ws = (char*)d_ws;
    _Float16* zhi   = (_Float16*)(ws);                  // [512][512] inp|h
    _Float16* zlo   = (_Float16*)(ws + 524288);
    float*    cbuf  = (float*)(ws + 1048576);           // [512][256]
    _Float16* xhi   = (_Float16*)(ws + 1572864);        // [512][2816]
    _Float16* xlo   = (_Float16*)(ws + 4456448);        // -> 7340032
    float*    ybuf  = (float*)(ws + 7340032);           // [512][2816] f32 acc
    float*    w2acc = (float*)(ws + 13107200);          // [512][320] f32 acc
    float*    ghh   = (float*)(ws + 13762560);          // [512][1024] ilv
    int*      ctrY  = (int*)(ws + 15859712);            // [88]
    int*      ctrW2 = (int*)(ws + 15860064);            // [40] -> 15860224
    _Float16* wihhi = (_Float16*)(ws + 15860224);       // [1024][256] ilv
    _Float16* wihlo = (_Float16*)(ws + 16384512);
    _Float16* whhhi = (_Float16*)(ws + 16908800);
    _Float16* whhlo = (_Float16*)(ws + 17433088);       // -> 17957376
    _Float16* w2vhi = (_Float16*)(ws + 17957376);       // [272][2816]
    _Float16* w2vlo = (_Float16*)(ws + 19489280);       // -> 21021184
    _Float16* w1hi  = (_Float16*)(ws + 21021184);       // [2816][2816]
    _Float16* w1lo  = (_Float16*)(ws + 36880896);       // -> 52740608
    _Float16* yhi   = (_Float16*)(ws + 52740608);       // [512][2816]
    _Float16* ylo   = (_Float16*)(ws + 55624192);       // -> 58507776 (<64MiB)

    // zero: z+c state; accumulators + ghh + counters
    hipMemsetAsync(ws, 0, 1572864, stream);
    hipMemsetAsync(ws + 7340032, 0, 15860224 - 7340032, stream);
    build_ilv<<<dim3(1024), dim3(256), 0, stream>>>(W_ih, W_hh, wihhi, wihlo, whhhi, whhlo);
    build_w2v<<<dim3(272), dim3(256), 0, stream>>>(W2, Wv, w2vhi, w2vlo);
    cvt_hilo<<<dim3(4096), dim3(256), 0, stream>>>(W1, w1hi, w1lo, SAW * SAW);

    for (int t = 0; t < TT; ++t) {
        // gates (inp part, +ghh(t-1)) -> LSTM -> h,c ; emb(t) -> x
        gates_lstm_emb<<<dim3(8, 16), dim3(256), 0, stream>>>(
            zhi, zlo, wihhi, wihlo, ghh, b_ih, b_hh, cbuf,
            zhi, zlo, xhi, xlo, desc, Wd, bd, t);
        // ghh(t) = h(t) @ W_hh^T (interleaved)
        ghh_gemm<<<dim3(8, 16), dim3(256), 0, stream>>>(zhi, zlo, whhhi, whhlo, ghh);
        // y = relu(x @ W1^T + b1) via atomic partials + last-tile finish
        w1_atomic<<<dim3(4, 22, 4), dim3(256), 0, stream>>>(
            xhi, xlo, w1hi, w1lo, ybuf, b1, yhi, ylo, ctrY);
        // inp(t+1) = relu(y @ W2^T + b2); out[t] = y @ Wv^T + bv
        w2v_atomic<<<dim3(8, 5, 4), dim3(256), 0, stream>>>(
            yhi, ylo, w2vhi, w2vlo, w2acc, b2, bv, zhi, zlo, out, ctrW2, t);
    }
}

// Round 8
// 10326.825 us; speedup vs baseline: 1.3323x; 1.3323x over previous
//
#include <hip/hip_runtime.h>
#include <hip/hip_bf16.h>
#include <math.h>

#define TT 100
#define ND 10
#define DS 6
#define SAW 2816

typedef _Float16 half8 __attribute__((ext_vector_type(8)));
typedef float floatx4 __attribute__((ext_vector_type(4)));

__device__ __forceinline__ void gload_lds16(const _Float16* g, _Float16* l) {
    __builtin_amdgcn_global_load_lds((const __attribute__((address_space(1))) void*)g,
                                     (__attribute__((address_space(3))) void*)l, 16, 0, 0);
}

// ---------------------------------------------------------------------------
// Split-fp16 3-pass MFMA GEMM, 2-phase pipelined (T3-minimum recipe):
// block 128x128, 512 thr = 8 waves (2M x 4N), wave tile 64x32 (4x2 frags of
// 16x16x32_f16), BK=32, double-buffered LDS (2 x 4 planes x 8KB = 64KB).
// Staging via global_load_lds w16; counted s_waitcnt vmcnt(4) (never 0 in
// steady state) so next-tile loads stay in flight across the barrier.
// EPI 0: f32 partial out (K-split via blockIdx.z). EPI 1: bias+relu+hi/lo.
// ---------------------------------------------------------------------------
template<int EPI>
__global__ __launch_bounds__(512) void gemm_pipe(
    const _Float16* __restrict__ Ah, const _Float16* __restrict__ Al, int lda,
    const _Float16* __restrict__ Bh, const _Float16* __restrict__ Bl, int ldb,
    const float* __restrict__ bias,
    float* __restrict__ Cf, size_t zstride,
    _Float16* __restrict__ Chi, _Float16* __restrict__ Clo,
    int ldc, int Kloc)
{
    __shared__ alignas(16) _Float16 lds[2][4][4096];   // [buf][plane][128*32]

    const int tid = threadIdx.x;
    const int w = tid >> 6, l = tid & 63;
    const int m0 = blockIdx.x * 128, n0 = blockIdx.y * 128;
    const int koff = blockIdx.z * Kloc;

    // staging: plane = w>>1 (0=Ah 1=Al 2=Bh 3=Bl); each wave does 4 chunks
    const int plane = w >> 1;
    const _Float16* psrc;
    int pld;
    if (plane == 0)      { psrc = Ah + (size_t)m0 * lda; pld = lda; }
    else if (plane == 1) { psrc = Al + (size_t)m0 * lda; pld = lda; }
    else if (plane == 2) { psrc = Bh + (size_t)n0 * ldb; pld = ldb; }
    else                 { psrc = Bl + (size_t)n0 * ldb; pld = ldb; }
    const int srow0 = (w & 1) * 64 + (l >> 2);   // +16*i
    const int scol = (l & 3) * 8;
    const int chnk0 = (w & 1) * 4;               // chunk-in-plane base

    // wave output sub-tile: 64 rows x 32 cols
    const int wr = (w >> 2) * 64, wc = (w & 3) * 32;
    const int fr = l & 15, fk = (l >> 4) * 8;

    floatx4 acc[4][2];
    const floatx4 z4 = {0.f, 0.f, 0.f, 0.f};
#pragma unroll
    for (int i = 0; i < 4; ++i)
#pragma unroll
        for (int j = 0; j < 2; ++j) acc[i][j] = z4;

#define STAGE(buf, kg)                                                          \
    {                                                                           \
        _Float16* const db = &lds[buf][plane][0];                               \
        _Pragma("unroll")                                                       \
        for (int i = 0; i < 4; ++i) {                                           \
            const int row = srow0 + i * 16;                                     \
            gload_lds16(psrc + (size_t)row * pld + (kg) + scol,                 \
                        db + (chnk0 + i) * 512);                                \
        }                                                                       \
    }

    STAGE(0, koff);
    int cur = 0;
    for (int kt = 0; kt < Kloc; kt += 32) {
        // barrier 1: all waves finished reading buf[cur^1] (previous iter)
        asm volatile("s_barrier" ::: "memory");
        if (kt + 32 < Kloc) {
            STAGE(cur ^ 1, koff + kt + 32);
            asm volatile("s_waitcnt vmcnt(4)" ::: "memory");   // cur's 4 landed
        } else {
            asm volatile("s_waitcnt vmcnt(0)" ::: "memory");
        }
        asm volatile("s_barrier" ::: "memory");                 // tile ready

        half8 aH[4], aL[4], bH[2], bL[2];
#pragma unroll
        for (int mf = 0; mf < 4; ++mf) {
            const int ro = (wr + mf * 16 + fr) * 32 + fk;
            aH[mf] = *(const half8*)&lds[cur][0][ro];
            aL[mf] = *(const half8*)&lds[cur][1][ro];
        }
#pragma unroll
        for (int nf = 0; nf < 2; ++nf) {
            const int ro = (wc + nf * 16 + fr) * 32 + fk;
            bH[nf] = *(const half8*)&lds[cur][2][ro];
            bL[nf] = *(const half8*)&lds[cur][3][ro];
        }
#pragma unroll
        for (int mf = 0; mf < 4; ++mf)
#pragma unroll
            for (int nf = 0; nf < 2; ++nf)
                acc[mf][nf] = __builtin_amdgcn_mfma_f32_16x16x32_f16(aH[mf], bH[nf], acc[mf][nf], 0, 0, 0);
#pragma unroll
        for (int mf = 0; mf < 4; ++mf)
#pragma unroll
            for (int nf = 0; nf < 2; ++nf)
                acc[mf][nf] = __builtin_amdgcn_mfma_f32_16x16x32_f16(aH[mf], bL[nf], acc[mf][nf], 0, 0, 0);
#pragma unroll
        for (int mf = 0; mf < 4; ++mf)
#pragma unroll
            for (int nf = 0; nf < 2; ++nf)
                acc[mf][nf] = __builtin_amdgcn_mfma_f32_16x16x32_f16(aL[mf], bH[nf], acc[mf][nf], 0, 0, 0);
        cur ^= 1;
    }
#undef STAGE

    // C/D layout: col = l&15, row = 4*(l>>4)+r
    const int cr = (l >> 4) * 4, cc = l & 15;
#pragma unroll
    for (int mf = 0; mf < 4; ++mf) {
        const int row = m0 + wr + mf * 16 + cr;
#pragma unroll
        for (int nf = 0; nf < 2; ++nf) {
            const int col = n0 + wc + nf * 16 + cc;
#pragma unroll
            for (int r = 0; r < 4; ++r) {
                float v = acc[mf][nf][r];
                if constexpr (EPI == 0) {
                    Cf[(size_t)blockIdx.z * zstride + (size_t)(row + r) * ldc + col] = v;
                } else {
                    v += bias[col];
                    v = v > 0.f ? v : 0.f;
                    const _Float16 h = (_Float16)v;
                    Chi[(size_t)(row + r) * ldc + col] = h;
                    Clo[(size_t)(row + r) * ldc + col] = (_Float16)(v - (float)h);
                }
            }
        }
    }
}

// ---------------------------------------------------------------------------
// 64x64 split-fp16 GEMM, reg-prefetch, K-split partial out (W2|Wv, ldc=320)
// ---------------------------------------------------------------------------
__global__ __launch_bounds__(256) void gemm_w2v(
    const _Float16* __restrict__ Ah, const _Float16* __restrict__ Al,
    const _Float16* __restrict__ Bh, const _Float16* __restrict__ Bl,
    float* __restrict__ Cf, int Kloc)
{
    __shared__ alignas(16) _Float16 sAh[64 * 32];
    __shared__ alignas(16) _Float16 sAl[64 * 32];
    __shared__ alignas(16) _Float16 sBh[64 * 32];
    __shared__ alignas(16) _Float16 sBl[64 * 32];

    const int tid = threadIdx.x, w = tid >> 6, l = tid & 63;
    const int m0 = blockIdx.x * 64, n0 = blockIdx.y * 64;
    const int koff = blockIdx.z * Kloc;

    const int sr = 16 * w + (l >> 2), sc = (l & 3) * 8, sidx = sr * 32 + sc;
    const _Float16* gAh = Ah + (size_t)(m0 + sr) * SAW + koff + sc;
    const _Float16* gAl = Al + (size_t)(m0 + sr) * SAW + koff + sc;
    const _Float16* gBh = Bh + (size_t)(n0 + sr) * SAW + koff + sc;
    const _Float16* gBl = Bl + (size_t)(n0 + sr) * SAW + koff + sc;

    const int mw = (w >> 1) * 32, nw = (w & 1) * 32;
    const int fr = l & 15, fk = (l >> 4) * 8;

    floatx4 acc[2][2];
    const floatx4 z4 = {0.f, 0.f, 0.f, 0.f};
#pragma unroll
    for (int i = 0; i < 2; ++i)
#pragma unroll
        for (int j = 0; j < 2; ++j) acc[i][j] = z4;

    half8 rAh = *(const half8*)gAh;
    half8 rAl = *(const half8*)gAl;
    half8 rBh = *(const half8*)gBh;
    half8 rBl = *(const half8*)gBl;

    for (int kt = 0; kt < Kloc; kt += 32) {
        *(half8*)&sAh[sidx] = rAh;
        *(half8*)&sAl[sidx] = rAl;
        *(half8*)&sBh[sidx] = rBh;
        *(half8*)&sBl[sidx] = rBl;
        __syncthreads();
        if (kt + 32 < Kloc) {
            rAh = *(const half8*)(gAh + kt + 32);
            rAl = *(const half8*)(gAl + kt + 32);
            rBh = *(const half8*)(gBh + kt + 32);
            rBl = *(const half8*)(gBl + kt + 32);
        }
        half8 aH[2], aL[2], bH[2], bL[2];
#pragma unroll
        for (int mf = 0; mf < 2; ++mf) {
            const int ro = (mw + mf * 16 + fr) * 32 + fk;
            aH[mf] = *(const half8*)&sAh[ro];
            aL[mf] = *(const half8*)&sAl[ro];
        }
#pragma unroll
        for (int nf = 0; nf < 2; ++nf) {
            const int ro = (nw + nf * 16 + fr) * 32 + fk;
            bH[nf] = *(const half8*)&sBh[ro];
            bL[nf] = *(const half8*)&sBl[ro];
        }
#pragma unroll
        for (int mf = 0; mf < 2; ++mf)
#pragma unroll
            for (int nf = 0; nf < 2; ++nf)
                acc[mf][nf] = __builtin_amdgcn_mfma_f32_16x16x32_f16(aH[mf], bH[nf], acc[mf][nf], 0, 0, 0);
#pragma unroll
        for (int mf = 0; mf < 2; ++mf)
#pragma unroll
            for (int nf = 0; nf < 2; ++nf)
                acc[mf][nf] = __builtin_amdgcn_mfma_f32_16x16x32_f16(aH[mf], bL[nf], acc[mf][nf], 0, 0, 0);
#pragma unroll
        for (int mf = 0; mf < 2; ++mf)
#pragma unroll
            for (int nf = 0; nf < 2; ++nf)
                acc[mf][nf] = __builtin_amdgcn_mfma_f32_16x16x32_f16(aL[mf], bH[nf], acc[mf][nf], 0, 0, 0);
        __syncthreads();
    }

    const int cr = (l >> 4) * 4, cc = l & 15;
#pragma unroll
    for (int nf = 0; nf < 2; ++nf) {
        const int col = n0 + nw + nf * 16 + cc;
#pragma unroll
        for (int mf = 0; mf < 2; ++mf) {
            const int row = m0 + mw + mf * 16 + cr;
#pragma unroll
            for (int r = 0; r < 4; ++r)
                Cf[(size_t)blockIdx.z * 163840 + (size_t)(row + r) * 320 + col]
                    = acc[mf][nf][r];
        }
    }
}

// ---------------------------------------------------------------------------
// fused LSTM elementwise (sums 4 gate partials + bias) + embedding
// ---------------------------------------------------------------------------
__global__ __launch_bounds__(256) void lstm_emb(
    const float* __restrict__ gpart, const float* __restrict__ b_ih,
    const float* __restrict__ b_hh, float* __restrict__ cbuf,
    _Float16* __restrict__ zhi, _Float16* __restrict__ zlo,
    _Float16* __restrict__ xhi, _Float16* __restrict__ xlo,
    const float* __restrict__ desc, const float* __restrict__ Wd,
    const float* __restrict__ bd, int t)
{
    __shared__ float sd[60];
    __shared__ float swd[1536];
    const int b = blockIdx.x, k = threadIdx.x;
    if (k < 60) sd[k] = desc[(size_t)b * (TT * ND * DS) + t * (ND * DS) + k];
    for (int i = k; i < 1536; i += 256) swd[i] = Wd[i];

    float gate[4];
#pragma unroll
    for (int g = 0; g < 4; ++g) {
        const int idx = g * 256 + k;
        float s = b_ih[idx] + b_hh[idx];
#pragma unroll
        for (int z = 0; z < 4; ++z) s += gpart[z * 524288 + b * 1024 + idx];
        gate[g] = s;
    }
    const float si = 1.f / (1.f + expf(-gate[0]));
    const float sf = 1.f / (1.f + expf(-gate[1]));
    const float so = 1.f / (1.f + expf(-gate[3]));
    float cv = cbuf[b * 256 + k];
    cv = sf * cv + si * tanhf(gate[2]);
    const float hv = so * tanhf(cv);
    cbuf[b * 256 + k] = cv;
    {
        const _Float16 h = (_Float16)hv;
        const _Float16 lo = (_Float16)(hv - (float)h);
        zhi[b * 512 + 256 + k] = h;   zlo[b * 512 + 256 + k] = lo;
        xhi[(size_t)b * SAW + 2560 + k] = h;
        xlo[(size_t)b * SAW + 2560 + k] = lo;
    }
    __syncthreads();

    const float bdv = bd[k];
#pragma unroll
    for (int n = 0; n < ND; ++n) {
        float a = bdv;
#pragma unroll
        for (int d = 0; d < DS; ++d) a += sd[n * DS + d] * swd[k * DS + d];
        const _Float16 h = (_Float16)a;
        xhi[(size_t)b * SAW + n * 256 + k] = h;
        xlo[(size_t)b * SAW + n * 256 + k] = (_Float16)(a - (float)h);
    }
}

// ---------------------------------------------------------------------------
// av_fin: sum 4 W2v partials; cols<256 -> relu+split -> z[:, :256];
// cols 256..265 -> out[b,t,:]
// ---------------------------------------------------------------------------
__global__ __launch_bounds__(256) void av_fin(
    const float* __restrict__ pbuf, const float* __restrict__ b2,
    const float* __restrict__ bv,
    _Float16* __restrict__ zhi, _Float16* __restrict__ zlo,
    float* __restrict__ out, int t)
{
    const int b = blockIdx.x, j = threadIdx.x;
    float s = b2[j];
#pragma unroll
    for (int z = 0; z < 4; ++z) s += pbuf[z * 163840 + b * 320 + j];
    s = s > 0.f ? s : 0.f;
    const _Float16 h = (_Float16)s;
    zhi[b * 512 + j] = h;
    zlo[b * 512 + j] = (_Float16)(s - (float)h);
    if (j < ND) {
        float s2 = bv[j];
#pragma unroll
        for (int z = 0; z < 4; ++z) s2 += pbuf[z * 163840 + b * 320 + 256 + j];
        out[(size_t)b * (TT * ND) + t * ND + j] = s2;
    }
}

// ---------------------------------------------------------------------------
// one-time prep
// ---------------------------------------------------------------------------
__global__ void build_wcat_split(const float* __restrict__ W_ih, const float* __restrict__ W_hh,
                                 _Float16* __restrict__ wchi, _Float16* __restrict__ wclo,
                                 float* __restrict__ bcat)
{
    const int j = blockIdx.x, k = threadIdx.x;
    const float v1 = W_ih[j * 256 + k];
    const _Float16 h1 = (_Float16)v1;
    wchi[j * 512 + k] = h1;
    wclo[j * 512 + k] = (_Float16)(v1 - (float)h1);
    const float v2 = W_hh[j * 256 + k];
    const _Float16 h2 = (_Float16)v2;
    wchi[j * 512 + 256 + k] = h2;
    wclo[j * 512 + 256 + k] = (_Float16)(v2 - (float)h2);
    if (k == 0) bcat[j] = 0.f;   // unused (biases added in lstm_emb)
}

__global__ __launch_bounds__(256) void build_w2v(const float* __restrict__ W2,
                                                 const float* __restrict__ Wv,
                                                 _Float16* __restrict__ hi,
                                                 _Float16* __restrict__ lo)
{
    const int j = blockIdx.x;                            // 0..319
    for (int k = threadIdx.x; k < SAW; k += 256) {
        float v = 0.f;
        if (j < 256)       v = W2[(size_t)j * SAW + k];
        else if (j < 266)  v = Wv[(size_t)(j - 256) * SAW + k];
        const _Float16 h = (_Float16)v;
        hi[(size_t)j * SAW + k] = h;
        lo[(size_t)j * SAW + k] = (_Float16)(v - (float)h);
    }
}

__global__ __launch_bounds__(256) void cvt_hilo(const float* __restrict__ src,
                                                _Float16* __restrict__ hi,
                                                _Float16* __restrict__ lo, int n)
{
    int i = blockIdx.x * 256 + threadIdx.x;
    const int stride = gridDim.x * 256;
    for (; i < n; i += stride) {
        const float v = src[i];
        const _Float16 h = (_Float16)v;
        hi[i] = h;
        lo[i] = (_Float16)(v - (float)h);
    }
}

// ---------------------------------------------------------------------------
extern "C" void kernel_launch(void* const* d_in, const int* in_sizes, int n_in,
                              void* d_out, int out_size, void* d_ws, size_t ws_size,
                              hipStream_t stream)
{
    const float* desc = (const float*)d_in[0];
    const float* Wd   = (const float*)d_in[1];
    const float* bd   = (const float*)d_in[2];
    const float* W1   = (const float*)d_in[3];
    const float* b1   = (const float*)d_in[4];
    const float* W2   = (const float*)d_in[5];
    const float* b2   = (const float*)d_in[6];
    const float* Wv   = (const float*)d_in[7];
    const float* bv   = (const float*)d_in[8];
    const float* W_ih = (const float*)d_in[9];
    const float* W_hh = (const float*)d_in[10];
    const float* b_ih = (const float*)d_in[11];
    const float* b_hh = (const float*)d_in[12];
    float* out = (float*)d_out;

    char* ws = (char*)d_ws;
    _Float16* zhi   = (_Float16*)(ws);                  // [512][512] inp|h
    _Float16* zlo   = (_Float16*)(ws + 524288);
    float*    cbuf  = (float*)(ws + 1048576);           // [512][256]
    _Float16* xhi   = (_Float16*)(ws + 1572864);        // [512][2816]
    _Float16* xlo   = (_Float16*)(ws + 4456448);        // -> 7340032
    float*    gpart = (float*)(ws + 7340032);           // [4][512][1024] f32
    float*    pbufW2= (float*)(ws + 15728640);          // [4][512][320] f32
    _Float16* yhi   = (_Float16*)(ws + 18350080);       // [512][2816]
    _Float16* ylo   = (_Float16*)(ws + 21233664);       // -> 24117248
    _Float16* wchi  = (_Float16*)(ws + 24117248);       // [1024][512]
    _Float16* wclo  = (_Float16*)(ws + 25165824);
    _Float16* w2vhi = (_Float16*)(ws + 26214400);       // [320][2816]
    _Float16* w2vlo = (_Float16*)(ws + 28016640);       // -> 29818880
    _Float16* w1hi  = (_Float16*)(ws + 29818880);       // [2816][2816]
    _Float16* w1lo  = (_Float16*)(ws + 45678592);       // -> 61538304
    float*    bcat  = (float*)(ws + 61538304);          // [1024]
    // end ~61.5 MB

    hipMemsetAsync(ws, 0, 1572864, stream);             // zero z, cbuf
    build_wcat_split<<<dim3(1024), dim3(256), 0, stream>>>(W_ih, W_hh, wchi, wclo, bcat);
    build_w2v<<<dim3(320), dim3(256), 0, stream>>>(W2, Wv, w2vhi, w2vlo);
    cvt_hilo<<<dim3(4096), dim3(256), 0, stream>>>(W1, w1hi, w1lo, SAW * SAW);

    for (int t = 0; t < TT; ++t) {
        // gates partials: z[512x512] . wcat^T[1024x512], K-split x4 (Kloc=128)
        gemm_pipe<0><<<dim3(4, 8, 4), dim3(512), 0, stream>>>(
            zhi, zlo, 512, wchi, wclo, 512, nullptr,
            gpart, 524288, nullptr, nullptr, 1024, 128);
        // LSTM (+bias) -> h,c -> z[:,256:], x[:,2560:]; emb(t) -> x
        lstm_emb<<<dim3(512), dim3(256), 0, stream>>>(gpart, b_ih, b_hh, cbuf,
                                                      zhi, zlo, xhi, xlo,
                                                      desc, Wd, bd, t);
        // y = relu(x . W1^T + b1) -> hi/lo, unsplit K=2816, fused epilogue
        gemm_pipe<1><<<dim3(4, 22, 1), dim3(512), 0, stream>>>(
            xhi, xlo, SAW, w1hi, w1lo, SAW, b1,
            nullptr, 0, yhi, ylo, SAW, SAW);
        // [W2|Wv] partials (K-split x4): N=320 (256 inp + 10 out + pad)
        gemm_w2v<<<dim3(8, 5, 4), dim3(256), 0, stream>>>(
            yhi, ylo, w2vhi, w2vlo, pbufW2, 704);
        // finish: inp(t+1) -> z[:, :256]; out[b,t,:]
        av_fin<<<dim3(512), dim3(256), 0, stream>>>(pbufW2, b2, bv, zhi, zlo, out, t);
    }
}

// Round 9
// 8233.736 us; speedup vs baseline: 1.6710x; 1.2542x over previous
//
#include <hip/hip_runtime.h>
#include <hip/hip_bf16.h>
#include <math.h>

#define TT 100
#define ND 10
#define DS 6
#define SAW 2816

typedef _Float16 half8 __attribute__((ext_vector_type(8)));
typedef float floatx4 __attribute__((ext_vector_type(4)));

__device__ __forceinline__ void gload_lds16(const _Float16* g, _Float16* l) {
    __builtin_amdgcn_global_load_lds((const __attribute__((address_space(1))) void*)g,
                                     (__attribute__((address_space(3))) void*)l, 16, 0, 0);
}

// ---------------------------------------------------------------------------
// Split-fp16 3-pass MFMA GEMM, 2-phase pipelined, XCD-swizzled, K-split.
// Flat 1-D grid (nwg = gm*gn*gz, % 8 == 0). Bijective XCD remap: hardware
// linear id round-robins XCDs (m09), so v = (id&7)*(nwg/8) + id>>3 gives each
// XCD a contiguous chunk of (m,n,z) groups -> B-panels fetched once per XCD.
// Block 128x128, 512 thr = 8 waves (2M x 4N), wave tile 64x32, BK=32,
// double-buffered LDS (64KB), global_load_lds w16, counted vmcnt(4).
// Output: f32 partial at Cf + z*zstride.
// ---------------------------------------------------------------------------
__global__ __launch_bounds__(512) void gemm_pipe(
    const _Float16* __restrict__ Ah, const _Float16* __restrict__ Al, int lda,
    const _Float16* __restrict__ Bh, const _Float16* __restrict__ Bl, int ldb,
    float* __restrict__ Cf, size_t zstride, int ldc, int Kloc, int gm, int gn)
{
    __shared__ alignas(16) _Float16 lds[2][4][4096];   // [buf][plane][128*32]

    const int nwg = gridDim.x;
    const int v = (blockIdx.x & 7) * (nwg >> 3) + (blockIdx.x >> 3);
    const int m0 = (v % gm) * 128;
    const int n0 = ((v / gm) % gn) * 128;
    const int zb = v / (gm * gn);
    const int koff = zb * Kloc;

    const int tid = threadIdx.x;
    const int w = tid >> 6, l = tid & 63;

    // staging: plane = w>>1 (0=Ah 1=Al 2=Bh 3=Bl); 2 waves per plane
    const int plane = w >> 1;
    const _Float16* psrc;
    int pld;
    if (plane == 0)      { psrc = Ah + (size_t)m0 * lda; pld = lda; }
    else if (plane == 1) { psrc = Al + (size_t)m0 * lda; pld = lda; }
    else if (plane == 2) { psrc = Bh + (size_t)n0 * ldb; pld = ldb; }
    else                 { psrc = Bl + (size_t)n0 * ldb; pld = ldb; }
    const int srow0 = (w & 1) * 64 + (l >> 2);
    const int scol = (l & 3) * 8;
    const int chnk0 = (w & 1) * 4;

    // wave output sub-tile: 64 rows x 32 cols
    const int wr = (w >> 2) * 64, wc = (w & 3) * 32;
    const int fr = l & 15, fk = (l >> 4) * 8;

    floatx4 acc[4][2];
    const floatx4 z4 = {0.f, 0.f, 0.f, 0.f};
#pragma unroll
    for (int i = 0; i < 4; ++i)
#pragma unroll
        for (int j = 0; j < 2; ++j) acc[i][j] = z4;

#define STAGE(buf, kg)                                                          \
    {                                                                           \
        _Float16* const db = &lds[buf][plane][0];                               \
        _Pragma("unroll")                                                       \
        for (int i = 0; i < 4; ++i) {                                           \
            const int row = srow0 + i * 16;                                     \
            gload_lds16(psrc + (size_t)row * pld + (kg) + scol,                 \
                        db + (chnk0 + i) * 512);                                \
        }                                                                       \
    }

    STAGE(0, koff);
    int cur = 0;
    for (int kt = 0; kt < Kloc; kt += 32) {
        asm volatile("s_barrier" ::: "memory");     // buf[cur^1] reads done
        if (kt + 32 < Kloc) {
            STAGE(cur ^ 1, koff + kt + 32);
            asm volatile("s_waitcnt vmcnt(4)" ::: "memory");   // cur's 4 landed
        } else {
            asm volatile("s_waitcnt vmcnt(0)" ::: "memory");
        }
        asm volatile("s_barrier" ::: "memory");     // tile ready

        half8 aH[4], aL[4], bH[2], bL[2];
#pragma unroll
        for (int mf = 0; mf < 4; ++mf) {
            const int ro = (wr + mf * 16 + fr) * 32 + fk;
            aH[mf] = *(const half8*)&lds[cur][0][ro];
            aL[mf] = *(const half8*)&lds[cur][1][ro];
        }
#pragma unroll
        for (int nf = 0; nf < 2; ++nf) {
            const int ro = (wc + nf * 16 + fr) * 32 + fk;
            bH[nf] = *(const half8*)&lds[cur][2][ro];
            bL[nf] = *(const half8*)&lds[cur][3][ro];
        }
#pragma unroll
        for (int mf = 0; mf < 4; ++mf)
#pragma unroll
            for (int nf = 0; nf < 2; ++nf)
                acc[mf][nf] = __builtin_amdgcn_mfma_f32_16x16x32_f16(aH[mf], bH[nf], acc[mf][nf], 0, 0, 0);
#pragma unroll
        for (int mf = 0; mf < 4; ++mf)
#pragma unroll
            for (int nf = 0; nf < 2; ++nf)
                acc[mf][nf] = __builtin_amdgcn_mfma_f32_16x16x32_f16(aH[mf], bL[nf], acc[mf][nf], 0, 0, 0);
#pragma unroll
        for (int mf = 0; mf < 4; ++mf)
#pragma unroll
            for (int nf = 0; nf < 2; ++nf)
                acc[mf][nf] = __builtin_amdgcn_mfma_f32_16x16x32_f16(aL[mf], bH[nf], acc[mf][nf], 0, 0, 0);
        cur ^= 1;
    }
#undef STAGE

    // C/D layout: col = l&15, row = 4*(l>>4)+r
    const int cr = (l >> 4) * 4, cc = l & 15;
#pragma unroll
    for (int mf = 0; mf < 4; ++mf) {
        const int row = m0 + wr + mf * 16 + cr;
#pragma unroll
        for (int nf = 0; nf < 2; ++nf) {
            const int col = n0 + wc + nf * 16 + cc;
#pragma unroll
            for (int r = 0; r < 4; ++r)
                Cf[(size_t)zb * zstride + (size_t)(row + r) * ldc + col] = acc[mf][nf][r];
        }
    }
}

// ---------------------------------------------------------------------------
// 64x64 split-fp16 GEMM, reg-prefetch, XCD-swizzled flat grid, K-split
// partial out (W2: ldc=256, zstride=512*256).
// ---------------------------------------------------------------------------
__global__ __launch_bounds__(256) void gemm_s16_part(
    const _Float16* __restrict__ Ah, const _Float16* __restrict__ Al, int lda,
    const _Float16* __restrict__ Bh, const _Float16* __restrict__ Bl, int ldb,
    float* __restrict__ Cf, int ldc, int Kloc, int gm, int gn)
{
    __shared__ alignas(16) _Float16 sAh[64 * 32];
    __shared__ alignas(16) _Float16 sAl[64 * 32];
    __shared__ alignas(16) _Float16 sBh[64 * 32];
    __shared__ alignas(16) _Float16 sBl[64 * 32];

    const int nwg = gridDim.x;
    const int v = (blockIdx.x & 7) * (nwg >> 3) + (blockIdx.x >> 3);
    const int m0 = (v % gm) * 64;
    const int n0 = ((v / gm) % gn) * 64;
    const int zb = v / (gm * gn);
    const int koff = zb * Kloc;

    const int tid = threadIdx.x, w = tid >> 6, l = tid & 63;
    const int sr = 16 * w + (l >> 2), sc = (l & 3) * 8, sidx = sr * 32 + sc;
    const _Float16* gAh = Ah + (size_t)(m0 + sr) * lda + koff + sc;
    const _Float16* gAl = Al + (size_t)(m0 + sr) * lda + koff + sc;
    const _Float16* gBh = Bh + (size_t)(n0 + sr) * ldb + koff + sc;
    const _Float16* gBl = Bl + (size_t)(n0 + sr) * ldb + koff + sc;

    const int mw = (w >> 1) * 32, nw = (w & 1) * 32;
    const int fr = l & 15, fk = (l >> 4) * 8;

    floatx4 acc[2][2];
    const floatx4 z4 = {0.f, 0.f, 0.f, 0.f};
#pragma unroll
    for (int i = 0; i < 2; ++i)
#pragma unroll
        for (int j = 0; j < 2; ++j) acc[i][j] = z4;

    half8 rAh = *(const half8*)gAh;
    half8 rAl = *(const half8*)gAl;
    half8 rBh = *(const half8*)gBh;
    half8 rBl = *(const half8*)gBl;

    for (int kt = 0; kt < Kloc; kt += 32) {
        *(half8*)&sAh[sidx] = rAh;
        *(half8*)&sAl[sidx] = rAl;
        *(half8*)&sBh[sidx] = rBh;
        *(half8*)&sBl[sidx] = rBl;
        __syncthreads();
        if (kt + 32 < Kloc) {
            rAh = *(const half8*)(gAh + kt + 32);
            rAl = *(const half8*)(gAl + kt + 32);
            rBh = *(const half8*)(gBh + kt + 32);
            rBl = *(const half8*)(gBl + kt + 32);
        }
        half8 aH[2], aL[2], bH[2], bL[2];
#pragma unroll
        for (int mf = 0; mf < 2; ++mf) {
            const int ro = (mw + mf * 16 + fr) * 32 + fk;
            aH[mf] = *(const half8*)&sAh[ro];
            aL[mf] = *(const half8*)&sAl[ro];
        }
#pragma unroll
        for (int nf = 0; nf < 2; ++nf) {
            const int ro = (nw + nf * 16 + fr) * 32 + fk;
            bH[nf] = *(const half8*)&sBh[ro];
            bL[nf] = *(const half8*)&sBl[ro];
        }
#pragma unroll
        for (int mf = 0; mf < 2; ++mf)
#pragma unroll
            for (int nf = 0; nf < 2; ++nf)
                acc[mf][nf] = __builtin_amdgcn_mfma_f32_16x16x32_f16(aH[mf], bH[nf], acc[mf][nf], 0, 0, 0);
#pragma unroll
        for (int mf = 0; mf < 2; ++mf)
#pragma unroll
            for (int nf = 0; nf < 2; ++nf)
                acc[mf][nf] = __builtin_amdgcn_mfma_f32_16x16x32_f16(aH[mf], bL[nf], acc[mf][nf], 0, 0, 0);
#pragma unroll
        for (int mf = 0; mf < 2; ++mf)
#pragma unroll
            for (int nf = 0; nf < 2; ++nf)
                acc[mf][nf] = __builtin_amdgcn_mfma_f32_16x16x32_f16(aL[mf], bH[nf], acc[mf][nf], 0, 0, 0);
        __syncthreads();
    }

    const int cr = (l >> 4) * 4, cc = l & 15;
#pragma unroll
    for (int nf = 0; nf < 2; ++nf) {
        const int col = n0 + nw + nf * 16 + cc;
#pragma unroll
        for (int mf = 0; mf < 2; ++mf) {
            const int row = m0 + mw + mf * 16 + cr;
#pragma unroll
            for (int r = 0; r < 4; ++r)
                Cf[(size_t)zb * (512 * 256) + (size_t)(row + r) * ldc + col]
                    = acc[mf][nf][r];
        }
    }
}

// ---------------------------------------------------------------------------
// y = relu(sum_z pbufY[z] + b1) -> hi/lo f16 planes
// ---------------------------------------------------------------------------
__global__ __launch_bounds__(256) void yred(const float* __restrict__ pbufY,
                                            const float* __restrict__ b1,
                                            _Float16* __restrict__ yhi,
                                            _Float16* __restrict__ ylo)
{
    const int b = blockIdx.x, tid = threadIdx.x;
    for (int i = tid; i < SAW; i += 256) {
        float s = b1[i];
#pragma unroll
        for (int z = 0; z < 4; ++z) s += pbufY[(size_t)z * 1441792 + (size_t)b * SAW + i];
        s = s > 0.f ? s : 0.f;
        const _Float16 h = (_Float16)s;
        yhi[(size_t)b * SAW + i] = h;
        ylo[(size_t)b * SAW + i] = (_Float16)(s - (float)h);
    }
}

// ---------------------------------------------------------------------------
// fused LSTM elementwise (sums 4 gate partials + bias) + embedding
// ---------------------------------------------------------------------------
__global__ __launch_bounds__(256) void lstm_emb(
    const float* __restrict__ gpart, const float* __restrict__ b_ih,
    const float* __restrict__ b_hh, float* __restrict__ cbuf,
    _Float16* __restrict__ zhi, _Float16* __restrict__ zlo,
    _Float16* __restrict__ xhi, _Float16* __restrict__ xlo,
    const float* __restrict__ desc, const float* __restrict__ Wd,
    const float* __restrict__ bd, int t)
{
    __shared__ float sd[60];
    __shared__ float swd[1536];
    const int b = blockIdx.x, k = threadIdx.x;
    if (k < 60) sd[k] = desc[(size_t)b * (TT * ND * DS) + t * (ND * DS) + k];
    for (int i = k; i < 1536; i += 256) swd[i] = Wd[i];

    float gate[4];
#pragma unroll
    for (int g = 0; g < 4; ++g) {
        const int idx = g * 256 + k;
        float s = b_ih[idx] + b_hh[idx];
#pragma unroll
        for (int z = 0; z < 4; ++z) s += gpart[z * 524288 + b * 1024 + idx];
        gate[g] = s;
    }
    const float si = 1.f / (1.f + expf(-gate[0]));
    const float sf = 1.f / (1.f + expf(-gate[1]));
    const float so = 1.f / (1.f + expf(-gate[3]));
    float cv = cbuf[b * 256 + k];
    cv = sf * cv + si * tanhf(gate[2]);
    const float hv = so * tanhf(cv);
    cbuf[b * 256 + k] = cv;
    {
        const _Float16 h = (_Float16)hv;
        const _Float16 lo = (_Float16)(hv - (float)h);
        zhi[b * 512 + 256 + k] = h;   zlo[b * 512 + 256 + k] = lo;
        xhi[(size_t)b * SAW + 2560 + k] = h;
        xlo[(size_t)b * SAW + 2560 + k] = lo;
    }
    __syncthreads();

    const float bdv = bd[k];
#pragma unroll
    for (int n = 0; n < ND; ++n) {
        float a = bdv;
#pragma unroll
        for (int d = 0; d < DS; ++d) a += sd[n * DS + d] * swd[k * DS + d];
        const _Float16 h = (_Float16)a;
        xhi[(size_t)b * SAW + n * 256 + k] = h;
        xlo[(size_t)b * SAW + n * 256 + k] = (_Float16)(a - (float)h);
    }
}

// ---------------------------------------------------------------------------
// fused: a = y.Wv^T + bv -> out[b,t,:]  AND  W2 partial reduce -> z[:, :256]
// ---------------------------------------------------------------------------
__global__ __launch_bounds__(256) void av_w2fin(
    const _Float16* __restrict__ yhi, const _Float16* __restrict__ ylo,
    const float* __restrict__ Wv, const float* __restrict__ bv,
    const float* __restrict__ pbuf, const float* __restrict__ b2,
    _Float16* __restrict__ zhi, _Float16* __restrict__ zlo,
    float* __restrict__ out, int t)
{
    __shared__ float ys[SAW];
    __shared__ float red[ND][4];
    const int b = blockIdx.x, tid = threadIdx.x;
    for (int i = tid; i < SAW; i += 256)
        ys[i] = (float)yhi[(size_t)b * SAW + i] + (float)ylo[(size_t)b * SAW + i];
    __syncthreads();

    float pacc[ND];
#pragma unroll
    for (int n = 0; n < ND; ++n) pacc[n] = 0.f;
    for (int kk = tid; kk < SAW; kk += 256) {
        const float yv = ys[kk];
#pragma unroll
        for (int n = 0; n < ND; ++n) pacc[n] += yv * Wv[n * SAW + kk];
    }
    const int lane = tid & 63, wid = tid >> 6;
#pragma unroll
    for (int n = 0; n < ND; ++n) {
        float v = pacc[n];
        for (int off = 32; off > 0; off >>= 1) v += __shfl_down(v, off, 64);
        if (lane == 0) red[n][wid] = v;
    }
    {
        const int j = tid;
        float s = b2[j];
#pragma unroll
        for (int kc = 0; kc < 4; ++kc) s += pbuf[kc * 131072 + b * 256 + j];
        s = s > 0.f ? s : 0.f;
        const _Float16 h = (_Float16)s;
        zhi[b * 512 + j] = h;
        zlo[b * 512 + j] = (_Float16)(s - (float)h);
    }
    __syncthreads();
    if (tid < ND) {
        const float s = red[tid][0] + red[tid][1] + red[tid][2] + red[tid][3] + bv[tid];
        out[(size_t)b * (TT * ND) + t * ND + tid] = s;
    }
}

// ---------------------------------------------------------------------------
// one-time prep
// ---------------------------------------------------------------------------
__global__ void build_wcat_split(const float* __restrict__ W_ih, const float* __restrict__ W_hh,
                                 _Float16* __restrict__ wchi, _Float16* __restrict__ wclo)
{
    const int j = blockIdx.x, k = threadIdx.x;
    const float v1 = W_ih[j * 256 + k];
    const _Float16 h1 = (_Float16)v1;
    wchi[j * 512 + k] = h1;
    wclo[j * 512 + k] = (_Float16)(v1 - (float)h1);
    const float v2 = W_hh[j * 256 + k];
    const _Float16 h2 = (_Float16)v2;
    wchi[j * 512 + 256 + k] = h2;
    wclo[j * 512 + 256 + k] = (_Float16)(v2 - (float)h2);
}

__global__ __launch_bounds__(256) void cvt_hilo(const float* __restrict__ src,
                                                _Float16* __restrict__ hi,
                                                _Float16* __restrict__ lo, int n)
{
    int i = blockIdx.x * 256 + threadIdx.x;
    const int stride = gridDim.x * 256;
    for (; i < n; i += stride) {
        const float v = src[i];
        const _Float16 h = (_Float16)v;
        hi[i] = h;
        lo[i] = (_Float16)(v - (float)h);
    }
}

// ---------------------------------------------------------------------------
extern "C" void kernel_launch(void* const* d_in, const int* in_sizes, int n_in,
                              void* d_out, int out_size, void* d_ws, size_t ws_size,
                              hipStream_t stream)
{
    const float* desc = (const float*)d_in[0];
    const float* Wd   = (const float*)d_in[1];
    const float* bd   = (const float*)d_in[2];
    const float* W1   = (const float*)d_in[3];
    const float* b1   = (const float*)d_in[4];
    const float* W2   = (const float*)d_in[5];
    const float* b2   = (const float*)d_in[6];
    const float* Wv   = (const float*)d_in[7];
    const float* bv   = (const float*)d_in[8];
    const float* W_ih = (const float*)d_in[9];
    const float* W_hh = (const float*)d_in[10];
    const float* b_ih = (const float*)d_in[11];
    const float* b_hh = (const float*)d_in[12];
    float* out = (float*)d_out;

    char* ws = (char*)d_ws;
    _Float16* zhi   = (_Float16*)(ws);                  // [512][512]
    _Float16* zlo   = (_Float16*)(ws + 524288);
    float*    cbuf  = (float*)(ws + 1048576);           // [512][256] f32
    _Float16* xhi   = (_Float16*)(ws + 1572864);        // [512][2816]
    _Float16* xlo   = (_Float16*)(ws + 4456448);
    _Float16* yhi   = xhi;                              // y aliases x
    _Float16* ylo   = xlo;
    // R region: gpart / pbufY / pbufW2 sequential lifetimes, alias base
    float*    gpart = (float*)(ws + 7340032);           // [4][512][1024]
    float*    pbufY = (float*)(ws + 7340032);           // [4][512][2816]
    float*    pbufW2= (float*)(ws + 7340032);           // [4][512][256]
    // weights (persistent)
    _Float16* wchi = (_Float16*)(ws + 30408704);        // [1024][512]
    _Float16* wclo = (_Float16*)(ws + 31457280);
    _Float16* w2hi = (_Float16*)(ws + 32505856);        // [256][2816]
    _Float16* w2lo = (_Float16*)(ws + 33947648);
    _Float16* w1hi = (_Float16*)(ws + 35389440);        // [2816][2816]
    _Float16* w1lo = (_Float16*)(ws + 51249152);
    // end = 67108864 B = 64 MiB exactly

    hipMemsetAsync(ws, 0, 1572864, stream);             // zero z, cbuf
    build_wcat_split<<<dim3(1024), dim3(256), 0, stream>>>(W_ih, W_hh, wchi, wclo);
    cvt_hilo<<<dim3(4096), dim3(256), 0, stream>>>(W1, w1hi, w1lo, SAW * SAW);
    cvt_hilo<<<dim3(704), dim3(256), 0, stream>>>(W2, w2hi, w2lo, 256 * SAW);

    for (int t = 0; t < TT; ++t) {
        // gates partials: z . wcat^T, M=512 N=1024, K-split x4 (Kloc=128)
        gemm_pipe<<<dim3(128), dim3(512), 0, stream>>>(
            zhi, zlo, 512, wchi, wclo, 512, gpart, 524288, 1024, 128, 4, 8);
        // LSTM (+bias) -> h,c -> z[:,256:], x[:,2560:]; emb(t) -> x
        lstm_emb<<<dim3(512), dim3(256), 0, stream>>>(gpart, b_ih, b_hh, cbuf,
                                                      zhi, zlo, xhi, xlo,
                                                      desc, Wd, bd, t);
        // W1 partials: x . W1^T, M=512 N=2816, K-split x4 (Kloc=704)
        gemm_pipe<<<dim3(352), dim3(512), 0, stream>>>(
            xhi, xlo, SAW, w1hi, w1lo, SAW, pbufY, 1441792, SAW, 704, 4, 22);
        // y = relu(sum + b1) -> hi/lo (aliases x region)
        yred<<<dim3(512), dim3(256), 0, stream>>>(pbufY, b1, yhi, ylo);
        // W2 partials (K-split x4)
        gemm_s16_part<<<dim3(128), dim3(256), 0, stream>>>(
            yhi, ylo, SAW, w2hi, w2lo, SAW, pbufW2, 256, 704, 8, 4);
        // out[t] = y.Wv^T + bv ; inp_next = relu(sum pbufW2 + b2) -> z[:, :256]
        av_w2fin<<<dim3(512), dim3(256), 0, stream>>>(yhi, ylo, Wv, bv, pbufW2, b2,
                                                      zhi, zlo, out, t);
    }
}